// Round 11
// baseline (307.687 us; speedup 1.0000x reference)
//
#include <hip/hip_runtime.h>
#include <hip/hip_fp16.h>

__device__ __forceinline__ float2 cmul(float2 a, float2 b) {
    return make_float2(a.x*b.x - a.y*b.y, a.x*b.y + a.y*b.x);
}
__device__ __forceinline__ float2 cadd(float2 a, float2 b){ return make_float2(a.x+b.x, a.y+b.y); }
__device__ __forceinline__ float2 csub(float2 a, float2 b){ return make_float2(a.x-b.x, a.y-b.y); }

// Wave-local LDS "barrier": all lane-exchange in the FFTs is within ONE wave
// (scratch regions are per-wave disjoint), so no s_barrier is needed. The
// CDNA DS pipe is in-order per wave; this only pins the compiler + drains
// lgkm before dependent reuse.
__device__ __forceinline__ void wsync() {
    asm volatile("s_waitcnt lgkmcnt(0)" ::: "memory");
}

// multiply by (0, SGN): forward SGN=-1, inverse SGN=+1
template<int SGN> __device__ __forceinline__ float2 mul_i(float2 a) {
    return (SGN > 0) ? make_float2(-a.y, a.x) : make_float2(a.y, -a.x);
}
// W8^1 = (r, SGN*r), r = sqrt(0.5)
template<int SGN> __device__ __forceinline__ float2 mul_w81(float2 a) {
    const float r = 0.70710678118654752440f;
    return (SGN > 0) ? make_float2(r*(a.x - a.y), r*(a.x + a.y))
                     : make_float2(r*(a.x + a.y), r*(a.y - a.x));
}
// W8^3 = (-r, SGN*r)
template<int SGN> __device__ __forceinline__ float2 mul_w83(float2 a) {
    const float r = 0.70710678118654752440f;
    return (SGN > 0) ? make_float2(-r*(a.x + a.y), r*(a.x - a.y))
                     : make_float2(r*(a.y - a.x), -r*(a.x + a.y));
}

// 8-point DFT in registers, natural-order output: out[q] = sum_k in[k] W8^{SGN*qk}
template<int SGN>
__device__ __forceinline__ void bfly8(float2 v[8]) {
    float2 s0 = cadd(v[0], v[4]), d0 = csub(v[0], v[4]);
    float2 s1 = cadd(v[1], v[5]), d1 = csub(v[1], v[5]);
    float2 s2 = cadd(v[2], v[6]), d2 = csub(v[2], v[6]);
    float2 s3 = cadd(v[3], v[7]), d3 = csub(v[3], v[7]);
    d1 = mul_w81<SGN>(d1);
    d2 = mul_i<SGN>(d2);
    d3 = mul_w83<SGN>(d3);
    float2 p0 = cadd(s0, s2), q0 = csub(s0, s2);
    float2 p1 = cadd(s1, s3), q1 = mul_i<SGN>(csub(s1, s3));
    float2 P0 = cadd(d0, d2), Q0 = csub(d0, d2);
    float2 P1 = cadd(d1, d3), Q1 = mul_i<SGN>(csub(d1, d3));
    v[0] = cadd(p0, p1);
    v[4] = csub(p0, p1);
    v[2] = cadd(q0, q1);
    v[6] = csub(q0, q1);
    v[1] = cadd(P0, P1);
    v[5] = csub(P0, P1);
    v[3] = cadd(Q0, Q1);
    v[7] = csub(Q0, Q1);
}

// v[q] *= W^{SGN*q}, W = cis(2*pi*frac)
template<int SGN>
__device__ __forceinline__ void twiddle7(float2 v[8], float frac) {
    const float ang = (SGN > 0 ? 6.2831853071795864769f : -6.2831853071795864769f) * frac;
    float sn, cs; __sincosf(ang, &sn, &cs);
    const float2 w1 = make_float2(cs, sn);
    float2 w = w1;
    v[1] = cmul(v[1], w);
#pragma unroll
    for (int q = 2; q < 8; ++q) { w = cmul(w, w1); v[q] = cmul(v[q], w); }
}

// Forward 512-pt FFT, one wave, lane l (0..63), v preloaded with h = l+64k.
// Output: v[q] = spectrum value at position p = 8l+q (freq = octal-digit-rev(p)).
// S: per-wave scratch, >= 575 float2. Wave-local sync only -- no block barriers.
__device__ __forceinline__ void fft512_fwd(float2 v[8], float2* S, int l) {
    const int g = l >> 3, j = l & 7;
    bfly8<-1>(v);
    twiddle7<-1>(v, (float)l * (1.0f/512.0f));
#pragma unroll
    for (int q = 0; q < 8; ++q) S[66*q + l] = v[q];          // f1(64q+l)
    wsync();
#pragma unroll
    for (int k = 0; k < 8; ++k) v[k] = S[66*g + j + 8*k];    // f1(64g+j+8k)
    bfly8<-1>(v);
    twiddle7<-1>(v, (float)j * (1.0f/64.0f));
#pragma unroll
    for (int q = 0; q < 8; ++q) S[72*g + 9*q + j] = v[q];    // f2(64g+8q+j)
    wsync();
#pragma unroll
    for (int k = 0; k < 8; ++k) v[k] = S[9*l + k];           // f2(8l+k)
    bfly8<-1>(v);
}

// Inverse (unscaled, x512): input v[q] = value at position 8l+q, output
// v[k] = natural-order sample at h = l+64k. Exact mirror of fft512_fwd.
__device__ __forceinline__ void fft512_inv(float2 v[8], float2* S, int l) {
    const int g = l >> 3, j = l & 7;
    bfly8<1>(v);
#pragma unroll
    for (int k = 0; k < 8; ++k) S[9*l + k] = v[k];
    wsync();
#pragma unroll
    for (int q = 0; q < 8; ++q) v[q] = S[72*g + 9*q + j];
    twiddle7<1>(v, (float)j * (1.0f/64.0f));
    bfly8<1>(v);
#pragma unroll
    for (int k = 0; k < 8; ++k) S[66*g + j + 8*k] = v[k];
    wsync();
#pragma unroll
    for (int q = 0; q < 8; ++q) v[q] = S[66*q + l];
    twiddle7<1>(v, (float)l * (1.0f/512.0f));
    bfly8<1>(v);
}

__device__ __forceinline__ int drev(int x) {   // reverse 3 octal digits of 9-bit x
    return ((x & 7) << 6) | (x & 56) | (x >> 6);
}

// ws intermediate is FP16 complex (__half2): halves all four intermediate
// streams. Full 1/512^2 normalization folded into Hp so pass2's fp16 output
// sits at |v| ~ 0.04 and pass3 needs no scale.

// Fused prologue + pass 1.
// Blocks 0..511: Hp[pw*512 + ph] = Hh[drev(ph)][drev(pw)] / 512^2, Hh =
// Hermitian part of the filter (for real x, Re(ifft2(fft2(x)*H)) ==
// ifft2(fft2(x)*Hh), a real linear map, so two planes pack as re/im).
// Blocks 512..8703: forward FFT along W, one row per wave.
// THIS ROUND: x is read as float4 (16 B/lane, 4 dwordx4 per wave instead of
// 16 scalar dwords) and redistributed to the FFT's stride-64 lane mapping
// through the per-wave LDS scratch -- testing whether memory-op issue/queue
// occupancy (not DRAM) is what caps our kernels at ~2.4 TB/s while float4
// copy hits 6.3.
__global__ __launch_bounds__(256) void pass1_rows(const float* __restrict__ x,
                                                  __half2* __restrict__ ws,
                                                  const float* __restrict__ Hr,
                                                  const float* __restrict__ Hi,
                                                  float2* __restrict__ Hp) {
    if (blockIdx.x < 512) {            // permH half
        const int pw = blockIdx.x;
        const int kw = drev(pw);
        const int nw = (512 - kw) & 511;
        const float s = 0.5f / (512.0f * 512.0f);
        for (int ph = threadIdx.x; ph < 512; ph += 256) {
            const int kh = drev(ph);
            const int nh = (512 - kh) & 511;
            const float hr = s * (Hr[(kh << 9) + kw] + Hr[(nh << 9) + nw]);
            const float hi = s * (Hi[(kh << 9) + kw] - Hi[(nh << 9) + nw]);
            Hp[(pw << 9) + ph] = make_float2(hr, hi);
        }
        return;
    }
    __shared__ float2 smem[4 * 577];
    const int t = threadIdx.x;
    const int l = t & 63, w = t >> 6;
    float2* S = smem + w * 577;
    const size_t row = (size_t)(blockIdx.x - 512) * 4 + w;  // 0..32767
    const size_t img = row >> 9;                     // packed plane 0..63
    const size_t h   = row & 511;
    const float* src1 = x + ((img * 2) << 18) + (h << 9);
    const float* src2 = src1 + (1 << 18);
    // float4 load + LDS redistribute to h = l + 64k lane mapping
    float4 a0 = ((const float4*)src1)[l];
    float4 a1 = ((const float4*)src1)[l + 64];
    float4 b0 = ((const float4*)src2)[l];
    float4 b1 = ((const float4*)src2)[l + 64];
    float* F = (float*)S;              // 1154 floats; use [0,1024)
    ((float4*)F)[l]        = a0;       // F[4l .. 4l+4)       = src1[4l..]
    ((float4*)F)[l + 64]   = a1;       // F[256+4l ..)
    ((float4*)F)[l + 128]  = b0;       // F[512+4l ..)        = src2[4l..]
    ((float4*)F)[l + 192]  = b1;       // F[768+4l ..)
    wsync();
    float2 v[8];
#pragma unroll
    for (int k = 0; k < 8; ++k)
        v[k] = make_float2(F[l + 64*k], F[512 + l + 64*k]);
    wsync();                           // reads done before FFT reuses S
    fft512_fwd(v, S, l);
    __half2 ob[8];
#pragma unroll
    for (int q = 0; q < 8; ++q) ob[q] = __float22half2_rn(v[q]);
    float4* dst = (float4*)(ws + row * 512 + 8*l);   // 32B contiguous per lane
    dst[0] = *(float4*)&ob[0];
    dst[1] = *(float4*)&ob[4];
}

// Pass 2 (unchanged from round 10): 16-column fp16 tiles (full 64 B/row
// footprint, no fetch amplification). 512 thr = 8 waves; each wave runs TWO
// column FFTs back-to-back. LDS staging fp16 half2, row stride 17 (coprime
// to 32 banks); staging (34.8 KB) aliases scratch (36.9 KB).
__global__ __launch_bounds__(512) void pass2_cols(__half2* __restrict__ ws,
                                                  const float2* __restrict__ Hp) {
    __shared__ float2 smem[4616];      // 8 scratches of 577 float2 = 36928 B
    __half2* sh = (__half2*)smem;      // staging view: [512 rows][stride 17]
    const int t = threadIdx.x;
    const int l = t & 63, w = t >> 6;  // wave id; wave handles cols 2w, 2w+1
    const int img = blockIdx.x >> 5;   // 0..63 packed planes
    const int w0 = (blockIdx.x & 31) * 16;   // 32 tiles of 16 columns
    __half2* base = ws + ((size_t)img << 18) + w0;

    {   // stage-in: 16B/lane = 4 half2; 4 chunks cover 64 B/row
        const int c = t & 3, u = t >> 2;     // c: 16B chunk, u: row 0..127
#pragma unroll
        for (int k = 0; k < 4; ++k) {
            int h = u + 128*k;
            float4 p = *(const float4*)(base + (size_t)h * 512 + 4*c);
            const __half2* pp = (const __half2*)&p;
#pragma unroll
            for (int i = 0; i < 4; ++i) sh[17*h + 4*c + i] = pp[i];
        }
    }
    __syncthreads();
    float2 va[8], vb[8];
    const int c0 = 2*w, c1 = 2*w + 1;
#pragma unroll
    for (int k = 0; k < 8; ++k) {
        va[k] = __half22float2(sh[17*(l + 64*k) + c0]);
        vb[k] = __half22float2(sh[17*(l + 64*k) + c1]);
    }
    __syncthreads();                   // staging dead; scratch may alias it
    float2* S = smem + w * 577;
    fft512_fwd(va, S, l);
    {   // filter col w0+c0: kh = drev(8l+q) pre-baked into Hp (incl. 1/512^2)
        const float4* hp = (const float4*)(Hp + (((size_t)(w0 + c0)) << 9) + 8*l);
#pragma unroll
        for (int q = 0; q < 4; ++q) {
            float4 h2 = hp[q];
            va[2*q]   = cmul(va[2*q],   make_float2(h2.x, h2.y));
            va[2*q+1] = cmul(va[2*q+1], make_float2(h2.z, h2.w));
        }
    }
    fft512_inv(va, S, l);
    fft512_fwd(vb, S, l);
    {   // filter col w0+c1
        const float4* hp = (const float4*)(Hp + (((size_t)(w0 + c1)) << 9) + 8*l);
#pragma unroll
        for (int q = 0; q < 4; ++q) {
            float4 h2 = hp[q];
            vb[2*q]   = cmul(vb[2*q],   make_float2(h2.x, h2.y));
            vb[2*q+1] = cmul(vb[2*q+1], make_float2(h2.z, h2.w));
        }
    }
    fft512_inv(vb, S, l);
    __syncthreads();                   // all waves done with scratch
#pragma unroll
    for (int k = 0; k < 8; ++k) {
        sh[17*(l + 64*k) + c0] = __float22half2_rn(va[k]);
        sh[17*(l + 64*k) + c1] = __float22half2_rn(vb[k]);
    }
    __syncthreads();
    {   // stage-out, mirror of stage-in
        const int c = t & 3, u = t >> 2;
#pragma unroll
        for (int k = 0; k < 4; ++k) {
            int h = u + 128*k;
            __half2 ob[4];
#pragma unroll
            for (int i = 0; i < 4; ++i) ob[i] = sh[17*h + 4*c + i];
            *(float4*)(base + (size_t)h * 512 + 4*c) = *(float4*)&ob[0];
        }
    }
}

// Pass 3: inverse FFT along W; unpack Re -> plane 2m, Im -> plane 2m+1.
// THIS ROUND: output gathered through LDS and stored as float4 (4 dwordx4
// per wave instead of 16 scalar dwords). Normalization folded into Hp.
__global__ __launch_bounds__(256) void pass3_rows(const __half2* __restrict__ ws,
                                                  float* __restrict__ out) {
    __shared__ float2 smem[4 * 577];
    const int t = threadIdx.x;
    const int l = t & 63, w = t >> 6;
    float2* S = smem + w * 577;
    const size_t row = (size_t)blockIdx.x * 4 + w;   // 0..32767
    const size_t img = row >> 9;                     // 0..63
    const size_t h   = row & 511;
    const float4* src = (const float4*)(ws + row * 512 + 8*l);
    float4 a = src[0], b = src[1];
    float2 v[8];
    {
        const __half2* pa = (const __half2*)&a;
        const __half2* pb = (const __half2*)&b;
#pragma unroll
        for (int k = 0; k < 4; ++k) v[k]     = __half22float2(pa[k]);
#pragma unroll
        for (int k = 0; k < 4; ++k) v[4 + k] = __half22float2(pb[k]);
    }
    fft512_inv(v, S, l);
    // scatter to LDS in natural order, then store float4-contiguous
    float* F = (float*)S;              // 1154 floats; use [0,1024)
    wsync();                           // inv's last S reads retired (in-order DS)
#pragma unroll
    for (int k = 0; k < 8; ++k) {
        F[l + 64*k]       = v[k].x;
        F[512 + l + 64*k] = v[k].y;
    }
    wsync();
    float* dst1 = out + ((img * 2) << 18) + (h << 9);
    float* dst2 = dst1 + (1 << 18);
    ((float4*)dst1)[l]      = ((float4*)F)[l];
    ((float4*)dst1)[l + 64] = ((float4*)F)[l + 64];
    ((float4*)dst2)[l]      = ((float4*)F)[l + 128];
    ((float4*)dst2)[l + 64] = ((float4*)F)[l + 192];
}

extern "C" void kernel_launch(void* const* d_in, const int* in_sizes, int n_in,
                              void* d_out, int out_size, void* d_ws, size_t ws_size,
                              hipStream_t stream) {
    const float* x  = (const float*)d_in[0];   // [8,16,512,512]
    const float* Hr = (const float*)d_in[1];   // [512,512]
    const float* Hi = (const float*)d_in[2];   // [512,512]
    float* out = (float*)d_out;
    __half2* ws = (__half2*)d_ws;              // 64 MiB fp16 workspace (64 packed planes)
    float2* Hp = (float2*)((char*)d_ws + ((size_t)64 << 20));  // 2 MiB filter after ws

    pass1_rows<<<8704, 256, 0, stream>>>(x, ws, Hr, Hi, Hp);  // permH fused in
    pass2_cols<<<2048, 512, 0, stream>>>(ws, Hp);
    pass3_rows<<<8192, 256, 0, stream>>>(ws, out);
}